// Round 6
// baseline (487.957 us; speedup 1.0000x reference)
//
#include <hip/hip_runtime.h>

// Problem constants (from setup_inputs): z (8,256,32,32), weight (16384,256)
#define NB   8
#define DIM  256
#define HW   1024          // 32*32
#define NZ   8192          // NB*HW flattened z rows
#define KC   16384         // codebook entries
#define DECAYF 0.99f
#define ONEMDECAY 0.01f
#define EPSF 1e-5f
#define BETAF 0.25f
#define BUCK_CAP 192u
#define OV_CAP   16384u

typedef _Float16 half8 __attribute__((ext_vector_type(8)));
typedef _Float16 half4 __attribute__((ext_vector_type(4)));
typedef float floatx4 __attribute__((ext_vector_type(4)));

// Output offsets (floats) in d_out, in reference return order
#define O_ZQ   0u
#define O_LOSS 2097152u
#define O_PERP 2097153u
#define O_IDX  2097154u
#define O_NW   2105346u
#define O_NCS  6299650u
#define O_NEA  6316034u

// ws layout (floats)
#define W_ZT     0u          // 8192*256 fp32
#define W_WSQ    2097152u    // 16384
#define W_CNT    2113536u    // 16384            (zeroed)
#define W_SCAL   2129920u    // 8: [0]=loss [1]=n_sum [2]=plogp [3]=maxB^2 (zeroed)
#define W_BCNT   2129928u    // 516: [0..511]=bucket counts, [512]=overflow cnt (zeroed)
#define W_PACKED 2130444u    // 8192 u64 (byte off %8==0)  (init by k_live / memset in fallback)
#define W_BUCK   2146828u    // 512*192 u32 bucketed worklist (row ids)
#define W_OVL    2245132u    // 16384 u32 overflow list (n<<9|j)
#define W_MINB   2261516u    // 8192*512 approx per-32-chunk minima
#define W_ACAT   6455820u    // 8192*256 f16  (byte off %16==0)
#define W_BCAT   7504396u    // 16384*256 f16 (byte off %16==0)
#define WS_FLOATS_MIN 2261516u
#define WS_FLOATS_NEW 9601548u

// ---------------- K0: transpose z (b,c,h,w) -> zt[n][d] (+ f16 Acat) ------------
template <bool SPLIT>
__global__ void k_transpose_in(const float* __restrict__ z, float* __restrict__ zt,
                               _Float16* __restrict__ Acat) {
  __shared__ float tile[64][65];
  int hwb = blockIdx.x * 64, db = blockIdx.y * 64, b = blockIdx.z;
  int lane = threadIdx.x & 63, sub = threadIdx.x >> 6;
#pragma unroll
  for (int i = 0; i < 16; ++i) {
    int dof = sub * 16 + i;
    tile[dof][lane] = z[((size_t)(b * DIM + db + dof)) * HW + hwb + lane];
  }
  __syncthreads();
#pragma unroll
  for (int i = 0; i < 16; ++i) {
    int hwof = sub * 16 + i;
    int n = b * HW + hwb + hwof;
    float val = tile[lane][hwof];
    zt[(size_t)n * DIM + db + lane] = val;
    if (SPLIT) Acat[(size_t)n * DIM + db + lane] = (_Float16)val;
  }
}

// ---------------- K5: transpose zt[n][d] (holds z_q_st) -> out0 (b,c,h,w) -------
__global__ void k_transpose_out(const float* __restrict__ zt, float* __restrict__ out0) {
  __shared__ float tile[64][65];
  int hwb = blockIdx.x * 64, db = blockIdx.y * 64, b = blockIdx.z;
  int lane = threadIdx.x & 63, sub = threadIdx.x >> 6;
#pragma unroll
  for (int i = 0; i < 16; ++i) {
    int hwof = sub * 16 + i;
    tile[hwof][lane] = zt[((size_t)(b * HW + hwb + hwof)) * DIM + db + lane];
  }
  __syncthreads();
#pragma unroll
  for (int i = 0; i < 16; ++i) {
    int dof = sub * 16 + i;
    out0[((size_t)(b * DIM + db + dof)) * HW + hwb + lane] = tile[lane][dof];
  }
}

// ---------------- K1: fused  wsq + maxB^2 + Bcat f16 + out6 = 0.99*ea -----------
template <bool SPLIT>
__global__ void k_prep(const float* __restrict__ w, const float* __restrict__ ea,
                       float* __restrict__ wsq, _Float16* __restrict__ Bcat,
                       float* __restrict__ out6, float* __restrict__ scal) {
  int wave = threadIdx.x >> 6, lane = threadIdx.x & 63;
  int k = blockIdx.x * 4 + wave;
  float4 v = *(const float4*)&w[(size_t)k * DIM + lane * 4];
  float s = v.x * v.x + v.y * v.y + v.z * v.z + v.w * v.w;
#pragma unroll
  for (int off = 32; off; off >>= 1) s += __shfl_xor(s, off);
  if (lane == 0) wsq[k] = s;
  if (SPLIT) {
    half4 h = { (_Float16)v.x, (_Float16)v.y, (_Float16)v.z, (_Float16)v.w };
    *(half4*)&Bcat[(size_t)k * DIM + lane * 4] = h;
  }
  float4 e = *(const float4*)&ea[(size_t)k * DIM + lane * 4];
  float4 o = { DECAYF * e.x, DECAYF * e.y, DECAYF * e.z, DECAYF * e.w };
  *(float4*)&out6[(size_t)k * DIM + lane * 4] = o;
  __shared__ float mx[4];
  if (lane == 0) mx[wave] = s;
  __syncthreads();
  if (threadIdx.x == 0)
    atomicMax((unsigned*)&scal[3],
              __float_as_uint(fmaxf(fmaxf(mx[0], mx[1]), fmaxf(mx[2], mx[3]))));
}

// ---------------- K2: approx f16 GEMM -> per-(row, 32-col-chunk) min score ------
#define GBM 128
#define GBN 128
#define GBK 64
#define NSTEP (DIM / GBK)   // 4

__device__ __forceinline__ void gload16(const _Float16* g, _Float16* lds) {
  __builtin_amdgcn_global_load_lds((__attribute__((address_space(1))) void*)g,
                                   (__attribute__((address_space(3))) void*)lds, 16, 0, 0);
}

#define WAITVM8   asm volatile("s_waitcnt vmcnt(8)" ::: "memory")
#define WAITVM0   asm volatile("s_waitcnt vmcnt(0)" ::: "memory")
#define WAITLGKM0 asm volatile("s_waitcnt lgkmcnt(0)" ::: "memory")
#define BAR       __builtin_amdgcn_s_barrier()

__global__ __launch_bounds__(256) void k_gemm_approx(const _Float16* __restrict__ Acat,
                                                     const _Float16* __restrict__ Bcat,
                                                     const float* __restrict__ wsq,
                                                     float* __restrict__ minb) {
  __shared__ __align__(16) _Float16 As[2][GBM * GBK];
  __shared__ __align__(16) _Float16 Bs[2][GBN * GBK];
  const int tid = threadIdx.x;
  const int w = tid >> 6, l = tid & 63;
  const int lr = l & 15, lc = l >> 4;
  const int wr = w >> 1, wc = w & 1;
  const int n0 = blockIdx.x * GBN, m0 = blockIdx.y * GBM;

  floatx4 acc[4][4];
#pragma unroll
  for (int i = 0; i < 4; ++i)
#pragma unroll
    for (int j = 0; j < 4; ++j) acc[i][j] = (floatx4){0.f, 0.f, 0.f, 0.f};

  const int srow = (l >> 3);
  const int schk = (l & 7);

#define STAGE(BUF, STEP)                                                          \
  {                                                                               \
    const int dbase_ = (STEP) * GBK;                                              \
    _Pragma("unroll")                                                             \
    for (int c = 0; c < 4; ++c) {                                                 \
      int row = (w * 4 + c) * 8 + srow;                                           \
      int sc_ = schk ^ (row & 7);                                                 \
      gload16(Acat + (size_t)(m0 + row) * DIM + dbase_ + sc_ * 8,                 \
              &As[BUF][(w * 4 + c) * 512]);                                       \
      gload16(Bcat + (size_t)(n0 + row) * DIM + dbase_ + sc_ * 8,                 \
              &Bs[BUF][(w * 4 + c) * 512]);                                       \
    }                                                                             \
  }

  STAGE(0, 0);
  STAGE(1, 1);

  for (int t = 0; t < NSTEP; ++t) {
    const int b = t & 1;
    if (t < NSTEP - 1) { WAITVM8; } else { WAITVM0; }
    BAR;
#pragma unroll
    for (int kk = 0; kk < 2; ++kk) {
      half8 af[4], bf[4];
#pragma unroll
      for (int mi = 0; mi < 4; ++mi) {
        int row = wr * 64 + mi * 16 + lr;
        int ch = (kk * 4 + lc) ^ (row & 7);
        af[mi] = *(const half8*)&As[b][row * GBK + ch * 8];
      }
#pragma unroll
      for (int ni = 0; ni < 4; ++ni) {
        int row = wc * 64 + ni * 16 + lr;
        int ch = (kk * 4 + lc) ^ (row & 7);
        bf[ni] = *(const half8*)&Bs[b][row * GBK + ch * 8];
      }
#pragma unroll
      for (int mi = 0; mi < 4; ++mi)
#pragma unroll
        for (int ni = 0; ni < 4; ++ni)
          acc[mi][ni] = __builtin_amdgcn_mfma_f32_16x16x32_f16(af[mi], bf[ni], acc[mi][ni], 0, 0, 0);
    }
    WAITLGKM0;
    BAR;
    if (t + 2 < NSTEP) STAGE(b, t + 2);
  }
#undef STAGE

  // epilogue: approx score = wsq - 2*dot; min per (row, 32-col chunk).
  float sc4[4];
#pragma unroll
  for (int ni = 0; ni < 4; ++ni) sc4[ni] = wsq[n0 + wc * 64 + ni * 16 + lr];
#pragma unroll
  for (int mi = 0; mi < 4; ++mi) {
#pragma unroll
    for (int r = 0; r < 4; ++r) {
      int row = m0 + wr * 64 + mi * 16 + lc * 4 + r;
#pragma unroll
      for (int jj = 0; jj < 2; ++jj) {
        float s0 = fmaf(-2.0f, acc[mi][2 * jj][r], sc4[2 * jj]);
        float s1 = fmaf(-2.0f, acc[mi][2 * jj + 1][r], sc4[2 * jj + 1]);
        float s = fminf(s0, s1);
#pragma unroll
        for (int off = 1; off < 16; off <<= 1) s = fminf(s, __shfl_xor(s, off));
        if (lr == 0) minb[(size_t)row * 512 + (n0 >> 5) + wc * 2 + jj] = s;
      }
    }
  }
}

// ---------------- B1: wave-per-row: anorm2, rowmin, packed-init, bucketed WL ----
__global__ __launch_bounds__(256) void k_live(const float* __restrict__ minb,
                                              const float* __restrict__ zt,
                                              const float* __restrict__ scal,
                                              unsigned* __restrict__ bcnt,
                                              unsigned* __restrict__ buckets,
                                              unsigned* __restrict__ ovl,
                                              unsigned long long* __restrict__ packed) {
  int wv = threadIdx.x >> 6, lane = threadIdx.x & 63;
  int n = blockIdx.x * 4 + wv;
  // ||z_n||^2 from zt
  float4 zv = *(const float4*)&zt[(size_t)n * DIM + lane * 4];
  float a2 = zv.x * zv.x + zv.y * zv.y + zv.z * zv.z + zv.w * zv.w;
#pragma unroll
  for (int off = 32; off; off >>= 1) a2 += __shfl_xor(a2, off);
  // chunk minima
  const float* row = &minb[(size_t)n * 512];
  float4 a = *(const float4*)&row[lane * 8];
  float4 b = *(const float4*)&row[lane * 8 + 4];
  float m = fminf(fminf(fminf(a.x, a.y), fminf(a.z, a.w)),
                  fminf(fminf(b.x, b.y), fminf(b.z, b.w)));
#pragma unroll
  for (int off = 1; off < 64; off <<= 1) m = fminf(m, __shfl_xor(m, off));
  float maxB = sqrtf(scal[3]);
  float E = 0.0022f * sqrtf(a2) * maxB + 1e-3f;   // sound |approx-exact| score bound
  float thr = m + 2.0f * E;
  if (lane == 0) packed[n] = ~0ull;
  float v[8] = {a.x, a.y, a.z, a.w, b.x, b.y, b.z, b.w};
#pragma unroll
  for (int c = 0; c < 8; ++c) {
    if (v[c] <= thr) {
      unsigned j = (unsigned)(lane * 8 + c);
      unsigned slot = atomicAdd(&bcnt[j], 1u);
      if (slot < BUCK_CAP) buckets[j * BUCK_CAP + slot] = (unsigned)n;
      else {
        unsigned s2 = atomicAdd(&bcnt[512], 1u);
        if (s2 < OV_CAP) ovl[s2] = ((unsigned)n << 9) | j;
      }
    }
  }
}

// ---------------- B2: exact fp32 re-score, chunk-bucketed (w in registers) ------
__global__ __launch_bounds__(256) void k_rescan(const unsigned* __restrict__ bcnt,
                                                const unsigned* __restrict__ buckets,
                                                const unsigned* __restrict__ ovl,
                                                const float* __restrict__ zt,
                                                const float* __restrict__ w,
                                                const float* __restrict__ wsq,
                                                unsigned long long* __restrict__ packed) {
  __shared__ float zs[DIM];
  const int tid = threadIdx.x;
  const int kl = tid >> 3, sub = tid & 7;
  if (blockIdx.x < 512) {
    int j = blockIdx.x;
    unsigned nb = bcnt[j];
    if (nb == 0) return;
    if (nb > BUCK_CAP) nb = BUCK_CAP;
    int k = j * 32 + kl;
    // stage this chunk's w into registers: thread holds w[k][sub*32 .. +32)
    float wreg[32];
    const float4* wr = (const float4*)&w[(size_t)k * DIM + sub * 32];
#pragma unroll
    for (int i = 0; i < 8; ++i) {
      float4 t = wr[i];
      wreg[4 * i] = t.x; wreg[4 * i + 1] = t.y; wreg[4 * i + 2] = t.z; wreg[4 * i + 3] = t.w;
    }
    float sq = wsq[k];
    for (unsigned e = 0; e < nb; ++e) {
      int n = (int)buckets[j * BUCK_CAP + e];
      __syncthreads();
      zs[tid] = zt[(size_t)n * DIM + tid];
      __syncthreads();
      float d = 0.f;
#pragma unroll
      for (int i = 0; i < 32; ++i) d = fmaf(wreg[i], zs[sub * 32 + i], d);
      d += __shfl_xor(d, 1); d += __shfl_xor(d, 2); d += __shfl_xor(d, 4);
      unsigned long long p = ~0ull;
      if (sub == 0) {
        float score = fmaf(-2.0f, d, sq);
        unsigned u = __float_as_uint(score);
        u ^= (unsigned)(((int)u >> 31) | 0x80000000);   // monotonic float->uint
        p = ((unsigned long long)u << 32) | (unsigned)k;
      }
#pragma unroll
      for (int off = 8; off < 64; off <<= 1) {
        unsigned long long o = __shfl_xor(p, off);
        p = o < p ? o : p;
      }
      if ((tid & 63) == 0) atomicMin(&packed[n], p);
    }
  } else {
    // overflow fallback: block per entry, w from global (practically never taken)
    unsigned cnt = bcnt[512];
    if (cnt > OV_CAP) cnt = OV_CAP;
    for (unsigned e = blockIdx.x - 512; e < cnt; e += 64) {
      unsigned ent = ovl[e];
      int n = (int)(ent >> 9), j = (int)(ent & 511u);
      __syncthreads();
      zs[tid] = zt[(size_t)n * DIM + tid];
      __syncthreads();
      int k = j * 32 + kl;
      const float* wr_ = &w[(size_t)k * DIM + sub * 32];
      float d = 0.f;
#pragma unroll
      for (int i = 0; i < 8; ++i) {
        float4 wv = *(const float4*)&wr_[i * 4];
        float4 z4 = *(const float4*)&zs[sub * 32 + i * 4];
        d = fmaf(wv.x, z4.x, d); d = fmaf(wv.y, z4.y, d);
        d = fmaf(wv.z, z4.z, d); d = fmaf(wv.w, z4.w, d);
      }
      d += __shfl_xor(d, 1); d += __shfl_xor(d, 2); d += __shfl_xor(d, 4);
      unsigned long long p = ~0ull;
      if (sub == 0) {
        float score = fmaf(-2.0f, d, wsq[k]);
        unsigned u = __float_as_uint(score);
        u ^= (unsigned)(((int)u >> 31) | 0x80000000);
        p = ((unsigned long long)u << 32) | (unsigned)k;
      }
#pragma unroll
      for (int off = 8; off < 64; off <<= 1) {
        unsigned long long o = __shfl_xor(p, off);
        p = o < p ? o : p;
      }
      if ((tid & 63) == 0) atomicMin(&packed[n], p);
    }
  }
}

// ---------------- Fallback fp32 GEMM+argmin -------------------------------------
#define TM 128
#define TN 128
#define DK 32
#define PADL 33
__global__ __launch_bounds__(256) void k_argmin_fp32(const float* __restrict__ zt,
                                                     const float* __restrict__ w,
                                                     const float* __restrict__ wsq,
                                                     unsigned long long* __restrict__ packed) {
  __shared__ float As[TM * PADL];
  __shared__ float Ws[TN * PADL];
  __shared__ unsigned long long best[TM];
  const int tid = threadIdx.x;
  const int k0 = blockIdx.x * TN, m0 = blockIdx.y * TM;
  if (tid < TM) best[tid] = ~0ull;
  const int tx = tid & 15, ty = tid >> 4;
  const int mrow = tid & 127;
  const int q = (tid >> 7) * 16;

  float acc[8][8];
#pragma unroll
  for (int i = 0; i < 8; ++i)
#pragma unroll
    for (int j = 0; j < 8; ++j) acc[i][j] = 0.0f;

  for (int dbase = 0; dbase < DIM; dbase += DK) {
    __syncthreads();
    const float* za = &zt[(size_t)(m0 + mrow) * DIM + dbase + q];
    const float* wa = &w[(size_t)(k0 + mrow) * DIM + dbase + q];
    float4 a0 = *(const float4*)(za + 0), a1 = *(const float4*)(za + 4);
    float4 a2 = *(const float4*)(za + 8), a3 = *(const float4*)(za + 12);
    float4 b0 = *(const float4*)(wa + 0), b1 = *(const float4*)(wa + 4);
    float4 b2 = *(const float4*)(wa + 8), b3 = *(const float4*)(wa + 12);
    float* Ap = &As[mrow * PADL + q];
    float* Wp = &Ws[mrow * PADL + q];
    Ap[0] = a0.x; Ap[1] = a0.y; Ap[2] = a0.z; Ap[3] = a0.w;
    Ap[4] = a1.x; Ap[5] = a1.y; Ap[6] = a1.z; Ap[7] = a1.w;
    Ap[8] = a2.x; Ap[9] = a2.y; Ap[10] = a2.z; Ap[11] = a2.w;
    Ap[12] = a3.x; Ap[13] = a3.y; Ap[14] = a3.z; Ap[15] = a3.w;
    Wp[0] = b0.x; Wp[1] = b0.y; Wp[2] = b0.z; Wp[3] = b0.w;
    Wp[4] = b1.x; Wp[5] = b1.y; Wp[6] = b1.z; Wp[7] = b1.w;
    Wp[8] = b2.x; Wp[9] = b2.y; Wp[10] = b2.z; Wp[11] = b2.w;
    Wp[12] = b3.x; Wp[13] = b3.y; Wp[14] = b3.z; Wp[15] = b3.w;
    __syncthreads();
#pragma unroll
    for (int d = 0; d < DK; ++d) {
      float a[8], b[8];
#pragma unroll
      for (int i = 0; i < 4; ++i) {
        a[i]     = As[(ty * 4 + i) * PADL + d];
        a[4 + i] = As[(64 + ty * 4 + i) * PADL + d];
        b[i]     = Ws[(tx * 4 + i) * PADL + d];
        b[4 + i] = Ws[(64 + tx * 4 + i) * PADL + d];
      }
#pragma unroll
      for (int i = 0; i < 8; ++i)
#pragma unroll
        for (int j = 0; j < 8; ++j) acc[i][j] = fmaf(a[i], b[j], acc[i][j]);
    }
  }

  float sc[8];
  int cols[8];
#pragma unroll
  for (int j = 0; j < 8; ++j) {
    int c = (j < 4) ? tx * 4 + j : 64 + tx * 4 + (j - 4);
    cols[j] = k0 + c;
    sc[j] = wsq[cols[j]];
  }
#pragma unroll
  for (int i = 0; i < 8; ++i) {
    int r = (i < 4) ? ty * 4 + i : 64 + ty * 4 + (i - 4);
    unsigned long long bv = ~0ull;
#pragma unroll
    for (int j = 0; j < 8; ++j) {
      float score = fmaf(-2.0f, acc[i][j], sc[j]);
      unsigned u = __float_as_uint(score);
      u ^= (unsigned)(((int)u >> 31) | 0x80000000);
      unsigned long long p = ((unsigned long long)u << 32) | (unsigned)cols[j];
      bv = p < bv ? p : bv;
    }
    atomicMin(&best[r], bv);
  }
  __syncthreads();
  if (tid < TM) atomicMin(&packed[m0 + tid], best[tid]);
}

// ---------------- K3: indices + counts + z_q gather + loss + embed scatter ------
__global__ __launch_bounds__(256) void k_scatter(float* __restrict__ zt,
                                                 const float* __restrict__ w,
                                                 const unsigned long long* __restrict__ packed,
                                                 float* __restrict__ emb_out,
                                                 float* __restrict__ loss_sum,
                                                 float* __restrict__ out3,
                                                 float* __restrict__ counts) {
  int n = blockIdx.x, d = threadIdx.x;
  int k = (int)(packed[n] & 0xFFFFFFFFull) & (KC - 1);
  if (d == 0) {
    out3[n] = (float)k;
    atomicAdd(&counts[k], 1.0f);
  }
  float zv = zt[(size_t)n * DIM + d];
  float wv = w[(size_t)k * DIM + d];
  float diff = wv - zv;                       // z_q - z_perm
  zt[(size_t)n * DIM + d] = zv + diff;        // straight-through
  atomicAdd(&emb_out[(size_t)k * DIM + d], ONEMDECAY * zv);
  float v = diff * diff;
#pragma unroll
  for (int off = 32; off; off >>= 1) v += __shfl_down(v, off);
  __shared__ float red[4];
  if ((threadIdx.x & 63) == 0) red[threadIdx.x >> 6] = v;
  __syncthreads();
  if (threadIdx.x == 0) atomicAdd(loss_sum, red[0] + red[1] + red[2] + red[3]);
}

// ---------------- K4a: new_cluster_size, n_sum, perplexity partial --------------
__global__ void k_cs(const float* __restrict__ cs, const float* __restrict__ counts,
                     float* __restrict__ out5, float* __restrict__ scal) {
  int k = blockIdx.x * 256 + threadIdx.x;
  float c = counts[k];
  float ncs = cs[k] * DECAYF + ONEMDECAY * c;
  out5[k] = ncs;
  float p = c * (1.0f / (float)NZ);
  float t = p * logf(p + 1e-10f);
#pragma unroll
  for (int off = 32; off; off >>= 1) {
    ncs += __shfl_down(ncs, off);
    t += __shfl_down(t, off);
  }
  __shared__ float r1[4], r2[4];
  if ((threadIdx.x & 63) == 0) { r1[threadIdx.x >> 6] = ncs; r2[threadIdx.x >> 6] = t; }
  __syncthreads();
  if (threadIdx.x == 0) {
    atomicAdd(&scal[1], r1[0] + r1[1] + r1[2] + r1[3]);
    atomicAdd(&scal[2], r2[0] + r2[1] + r2[2] + r2[3]);
  }
}

// ---------------- K4b: new_weight + scalars -------------------------------------
__global__ void k_final(const float* __restrict__ emb_out, const float* __restrict__ out5,
                        const float* __restrict__ scal, float* __restrict__ out4,
                        float* __restrict__ out1, float* __restrict__ out2) {
  size_t i = (size_t)blockIdx.x * 256 + threadIdx.x;
  float n = scal[1];
  int k = (int)(i >> 8);
  float ncs = out5[k];
  float smoothed = (ncs + EPSF) / (n + (float)KC * EPSF) * n;
  out4[i] = emb_out[i] / smoothed;
  if (i == 0) {
    out1[0] = BETAF * scal[0] / (float)(NZ * DIM);
    out2[0] = expf(-scal[2]);
  }
}

extern "C" void kernel_launch(void* const* d_in, const int* in_sizes, int n_in,
                              void* d_out, int out_size, void* d_ws, size_t ws_size,
                              hipStream_t stream) {
  const float* z  = (const float*)d_in[0];
  const float* w  = (const float*)d_in[1];
  const float* cs = (const float*)d_in[2];
  const float* ea = (const float*)d_in[3];
  float* out = (float*)d_out;
  float* ws  = (float*)d_ws;

  if (ws_size < (size_t)WS_FLOATS_MIN * sizeof(float)) return;  // fail loudly
  const bool use_mfma = ws_size >= (size_t)WS_FLOATS_NEW * sizeof(float);

  float* zt      = ws + W_ZT;
  float* wsq     = ws + W_WSQ;
  float* counts  = ws + W_CNT;
  float* scal    = ws + W_SCAL;
  unsigned* bcnt = (unsigned*)(ws + W_BCNT);
  unsigned long long* packed = (unsigned long long*)(ws + W_PACKED);
  unsigned* buckets = (unsigned*)(ws + W_BUCK);
  unsigned* ovl  = (unsigned*)(ws + W_OVL);
  float* minb    = ws + W_MINB;
  _Float16* Acat = (_Float16*)(ws + W_ACAT);
  _Float16* Bcat = (_Float16*)(ws + W_BCAT);

  float* out0 = out + O_ZQ;
  float* out1 = out + O_LOSS;
  float* out2 = out + O_PERP;
  float* out3 = out + O_IDX;
  float* out4 = out + O_NW;
  float* out5 = out + O_NCS;
  float* out6 = out + O_NEA;

  // zero counts + scal + bucket counts (contiguous)
  hipMemsetAsync(counts, 0, (16384 + 8 + 516) * sizeof(float), stream);

  if (use_mfma) {
    k_prep<true><<<KC / 4, 256, 0, stream>>>(w, ea, wsq, Bcat, out6, scal);
    k_transpose_in<true><<<dim3(16, 4, NB), 256, 0, stream>>>(z, zt, Acat);
    k_gemm_approx<<<dim3(KC / GBN, NZ / GBM), 256, 0, stream>>>(Acat, Bcat, wsq, minb);
    k_live<<<NZ / 4, 256, 0, stream>>>(minb, zt, scal, bcnt, buckets, ovl, packed);
    k_rescan<<<512 + 64, 256, 0, stream>>>(bcnt, buckets, ovl, zt, w, wsq, packed);
  } else {
    hipMemsetAsync(packed, 0xFF, (size_t)NZ * sizeof(unsigned long long), stream);
    k_prep<false><<<KC / 4, 256, 0, stream>>>(w, ea, wsq, Bcat, out6, scal);
    k_transpose_in<false><<<dim3(16, 4, NB), 256, 0, stream>>>(z, zt, Acat);
    k_argmin_fp32<<<dim3(KC / TN, NZ / TM), 256, 0, stream>>>(zt, w, wsq, packed);
  }
  k_scatter<<<NZ, 256, 0, stream>>>(zt, w, packed, out6, scal, out3, counts);
  k_cs<<<KC / 256, 256, 0, stream>>>(cs, counts, out5, scal);
  k_final<<<(KC * DIM) / 256, 256, 0, stream>>>(out6, out5, scal, out4, out1, out2);
  k_transpose_out<<<dim3(16, 4, NB), 256, 0, stream>>>(zt, out0);
}

// Round 7
// 432.214 us; speedup vs baseline: 1.1290x; 1.1290x over previous
//
#include <hip/hip_runtime.h>

// Problem constants (from setup_inputs): z (8,256,32,32), weight (16384,256)
#define NB   8
#define DIM  256
#define HW   1024          // 32*32
#define NZ   8192          // NB*HW flattened z rows
#define KC   16384         // codebook entries
#define DECAYF 0.99f
#define ONEMDECAY 0.01f
#define EPSF 1e-5f
#define BETAF 0.25f
#define KCAT 768           // split-GEMM K: [ah|al|ah] . [bh|bh|bl]

typedef _Float16 half8 __attribute__((ext_vector_type(8)));
typedef _Float16 half4 __attribute__((ext_vector_type(4)));
typedef float floatx4 __attribute__((ext_vector_type(4)));

// Output offsets (floats) in d_out, in reference return order
#define O_ZQ   0u
#define O_LOSS 2097152u
#define O_PERP 2097153u
#define O_IDX  2097154u
#define O_NW   2105346u
#define O_NCS  6299650u
#define O_NEA  6316034u

// ws layout (floats)
#define W_ZT     0u          // 8192*256 fp32
#define W_WSQ    2097152u    // 16384
#define W_CNT    2113536u    // 16384           (zeroed)
#define W_SCAL   2129920u    // 4: [0]=loss [1]=n_sum [2]=plogp (zeroed)
#define W_PACKED 2129924u    // 8192 u64 (byte off %8==0) (memset 0xFF)
#define W_ACAT   2146308u    // 8192*768 f16 (byte off %16==0)
#define W_BCAT   5292036u    // 16384*768 f16 (byte off %16==0)
#define WS_FLOATS_OLD 2146308u
#define WS_FLOATS_NEW 11583492u

// ---------------- K0: transpose z (b,c,h,w) -> zt[n][d] (+ f16 3-seg Acat) ------
// Acat segments: [ah | al | ah] so that with Bcat = [bh | bh | bl]:
//   dot = ah.bh + al.bh + ah.bl  (compensated; only al.bl ~1e-5 dropped)
template <bool SPLIT>
__global__ void k_transpose_in(const float* __restrict__ z, float* __restrict__ zt,
                               _Float16* __restrict__ Acat) {
  __shared__ float tile[64][65];
  int hwb = blockIdx.x * 64, db = blockIdx.y * 64, b = blockIdx.z;
  int lane = threadIdx.x & 63, sub = threadIdx.x >> 6;
#pragma unroll
  for (int i = 0; i < 16; ++i) {
    int dof = sub * 16 + i;
    tile[dof][lane] = z[((size_t)(b * DIM + db + dof)) * HW + hwb + lane];
  }
  __syncthreads();
#pragma unroll
  for (int i = 0; i < 16; ++i) {
    int hwof = sub * 16 + i;
    int n = b * HW + hwb + hwof;
    float val = tile[lane][hwof];
    zt[(size_t)n * DIM + db + lane] = val;
    if (SPLIT) {
      _Float16 h = (_Float16)val;
      _Float16 lo = (_Float16)(val - (float)h);
      size_t abase = (size_t)n * KCAT + db + lane;
      Acat[abase] = h;          // seg0 = ah
      Acat[abase + 256] = lo;   // seg1 = al (pairs with bh)
      Acat[abase + 512] = h;    // seg2 = ah (pairs with bl)
    }
  }
}

// ---------------- K5: transpose zt[n][d] (holds z_q_st) -> out0 (b,c,h,w) -------
__global__ void k_transpose_out(const float* __restrict__ zt, float* __restrict__ out0) {
  __shared__ float tile[64][65];
  int hwb = blockIdx.x * 64, db = blockIdx.y * 64, b = blockIdx.z;
  int lane = threadIdx.x & 63, sub = threadIdx.x >> 6;
#pragma unroll
  for (int i = 0; i < 16; ++i) {
    int hwof = sub * 16 + i;
    tile[hwof][lane] = zt[((size_t)(b * HW + hwb + hwof)) * DIM + db + lane];
  }
  __syncthreads();
#pragma unroll
  for (int i = 0; i < 16; ++i) {
    int dof = sub * 16 + i;
    out0[((size_t)(b * DIM + db + dof)) * HW + hwb + lane] = tile[lane][dof];
  }
}

// ---------------- K1: fused  wsq + 3-seg Bcat + out6 = 0.99*ea -------------------
template <bool SPLIT>
__global__ void k_prep(const float* __restrict__ w, const float* __restrict__ ea,
                       float* __restrict__ wsq, _Float16* __restrict__ Bcat,
                       float* __restrict__ out6) {
  int wave = threadIdx.x >> 6, lane = threadIdx.x & 63;
  int k = blockIdx.x * 4 + wave;
  float4 v = *(const float4*)&w[(size_t)k * DIM + lane * 4];
  float s = v.x * v.x + v.y * v.y + v.z * v.z + v.w * v.w;
#pragma unroll
  for (int off = 32; off; off >>= 1) s += __shfl_xor(s, off);
  if (lane == 0) wsq[k] = s;
  if (SPLIT) {
    half4 h = { (_Float16)v.x, (_Float16)v.y, (_Float16)v.z, (_Float16)v.w };
    half4 lo = { (_Float16)(v.x - (float)h.x), (_Float16)(v.y - (float)h.y),
                 (_Float16)(v.z - (float)h.z), (_Float16)(v.w - (float)h.w) };
    size_t bbase = (size_t)k * KCAT + lane * 4;
    *(half4*)&Bcat[bbase] = h;          // seg0 = bh
    *(half4*)&Bcat[bbase + 256] = h;    // seg1 = bh
    *(half4*)&Bcat[bbase + 512] = lo;   // seg2 = bl
  }
  float4 e = *(const float4*)&ea[(size_t)k * DIM + lane * 4];
  float4 o = { DECAYF * e.x, DECAYF * e.y, DECAYF * e.z, DECAYF * e.w };
  *(float4*)&out6[(size_t)k * DIM + lane * 4] = o;
}

// ---------------- K2: 256x256 MFMA distance GEMM + fused argmin ------------------
// 8 waves (2M x 4N), per-wave output 128x64 (8x4 16x16 frags): 24 ds_read_b128
// per 64 MFMA per K-step (0.375 reads/MFMA vs 1.0 for the 128^2 tile).
#define GBM 256
#define GBN 256
#define GBK 64
#define NSTEP (KCAT / GBK)   // 12

__device__ __forceinline__ void gload16(const _Float16* g, _Float16* lds) {
  __builtin_amdgcn_global_load_lds((__attribute__((address_space(1))) void*)g,
                                   (__attribute__((address_space(3))) void*)lds, 16, 0, 0);
}

#define WAITVM8   asm volatile("s_waitcnt vmcnt(8)" ::: "memory")
#define WAITVM0   asm volatile("s_waitcnt vmcnt(0)" ::: "memory")
#define WAITLGKM0 asm volatile("s_waitcnt lgkmcnt(0)" ::: "memory")
#define BAR       __builtin_amdgcn_s_barrier()

__global__ __launch_bounds__(512, 2) void k_argmin_mfma(const _Float16* __restrict__ Acat,
                                                        const _Float16* __restrict__ Bcat,
                                                        const float* __restrict__ wsq,
                                                        unsigned long long* __restrict__ packed) {
  __shared__ __align__(16) _Float16 As[2][GBM * GBK];   // 64 KB
  __shared__ __align__(16) _Float16 Bs[2][GBN * GBK];   // 64 KB  (total 128 KB)
  const int tid = threadIdx.x;
  const int w = tid >> 6, l = tid & 63;
  const int lr = l & 15, lc = l >> 4;
  const int wr = w >> 2, wc = w & 3;
  // bijective XCD swizzle (2048 blocks % 8 == 0): each XCD owns contiguous work
  const int bid = (int)blockIdx.x;
  const int swz = (bid & 7) * 256 + (bid >> 3);
  const int n0 = (swz & 63) * GBN;          // x-major: swz = by*64 + bx
  const int m0 = (swz >> 6) * GBM;

  floatx4 acc[8][4];
#pragma unroll
  for (int i = 0; i < 8; ++i)
#pragma unroll
    for (int j = 0; j < 4; ++j) acc[i][j] = (floatx4){0.f, 0.f, 0.f, 0.f};

  // staging: LDS linear dest; global source pre-swizzled chunk^(row&7) so the
  // frag ds_read_b128 (row stride 128B) is bank-conflict-free.
  const int srow = (l >> 3);
  const int schk = (l & 7);

  // 8 gloads per thread per K-step: 4 A row-groups + 4 B row-groups of 8 rows.
#define STAGE(BUF, STEP)                                                          \
  {                                                                               \
    const int dbase_ = (STEP) * GBK;                                              \
    _Pragma("unroll")                                                             \
    for (int c = 0; c < 4; ++c) {                                                 \
      int row = (w * 4 + c) * 8 + srow;                                           \
      int sc_ = schk ^ (row & 7);                                                 \
      gload16(Acat + (size_t)(m0 + row) * KCAT + dbase_ + sc_ * 8,                \
              &As[BUF][(w * 4 + c) * 512]);                                       \
      gload16(Bcat + (size_t)(n0 + row) * KCAT + dbase_ + sc_ * 8,                \
              &Bs[BUF][(w * 4 + c) * 512]);                                       \
    }                                                                             \
  }

  STAGE(0, 0);
  STAGE(1, 1);

  for (int t = 0; t < NSTEP; ++t) {
    const int b = t & 1;
    if (t < NSTEP - 1) { WAITVM8; } else { WAITVM0; }
    BAR;                                   // all waves' tile-t loads landed
#pragma unroll
    for (int kk = 0; kk < 2; ++kk) {
      half8 af[8], bf[4];
#pragma unroll
      for (int mi = 0; mi < 8; ++mi) {
        int row = wr * 128 + mi * 16 + lr;
        int ch = (kk * 4 + lc) ^ (row & 7);
        af[mi] = *(const half8*)&As[b][row * GBK + ch * 8];
      }
#pragma unroll
      for (int ni = 0; ni < 4; ++ni) {
        int row = wc * 64 + ni * 16 + lr;
        int ch = (kk * 4 + lc) ^ (row & 7);
        bf[ni] = *(const half8*)&Bs[b][row * GBK + ch * 8];
      }
#pragma unroll
      for (int mi = 0; mi < 8; ++mi)
#pragma unroll
        for (int ni = 0; ni < 4; ++ni)
          acc[mi][ni] = __builtin_amdgcn_mfma_f32_16x16x32_f16(af[mi], bf[ni], acc[mi][ni], 0, 0, 0);
    }
    WAITLGKM0;                             // my ds_reads of buf b complete
    BAR;                                   // everyone done reading buf b
    if (t + 2 < NSTEP) STAGE(b, t + 2);    // overwrite freed buffer
  }
#undef STAGE

  // epilogue: per-row argmin. C layout: col = lane&15, row = (lane>>4)*4 + reg.
  // best[] aliases the now-dead A buffer (last BAR above guarantees all reads done).
  unsigned long long* best = (unsigned long long*)&As[0][0];
  if (tid < GBM) best[tid] = ~0ull;
  __syncthreads();
  float sc4[4];
  int col4[4];
#pragma unroll
  for (int ni = 0; ni < 4; ++ni) {
    col4[ni] = n0 + wc * 64 + ni * 16 + lr;
    sc4[ni] = wsq[col4[ni]];
  }
#pragma unroll
  for (int mi = 0; mi < 8; ++mi) {
#pragma unroll
    for (int r = 0; r < 4; ++r) {
      unsigned long long bv = ~0ull;
#pragma unroll
      for (int ni = 0; ni < 4; ++ni) {
        float score = fmaf(-2.0f, acc[mi][ni][r], sc4[ni]);
        unsigned u = __float_as_uint(score);
        u ^= (unsigned)(((int)u >> 31) | 0x80000000);  // monotonic float->uint
        unsigned long long p = ((unsigned long long)u << 32) | (unsigned)col4[ni];
        bv = p < bv ? p : bv;
      }
#pragma unroll
      for (int off = 1; off < 16; off <<= 1) {
        unsigned long long o = __shfl_xor(bv, off);
        bv = o < bv ? o : bv;
      }
      if (lr == 0) atomicMin(&best[wr * 128 + mi * 16 + lc * 4 + r], bv);
    }
  }
  __syncthreads();
  if (tid < GBM) atomicMin(&packed[m0 + tid], best[tid]);
}

// ---------------- Fallback fp32 GEMM+argmin -------------------------------------
#define TM 128
#define TN 128
#define DK 32
#define PADL 33
__global__ __launch_bounds__(256) void k_argmin_fp32(const float* __restrict__ zt,
                                                     const float* __restrict__ w,
                                                     const float* __restrict__ wsq,
                                                     unsigned long long* __restrict__ packed) {
  __shared__ float As[TM * PADL];
  __shared__ float Ws[TN * PADL];
  __shared__ unsigned long long best[TM];
  const int tid = threadIdx.x;
  const int k0 = blockIdx.x * TN, m0 = blockIdx.y * TM;
  if (tid < TM) best[tid] = ~0ull;
  const int tx = tid & 15, ty = tid >> 4;
  const int mrow = tid & 127;
  const int q = (tid >> 7) * 16;

  float acc[8][8];
#pragma unroll
  for (int i = 0; i < 8; ++i)
#pragma unroll
    for (int j = 0; j < 8; ++j) acc[i][j] = 0.0f;

  for (int dbase = 0; dbase < DIM; dbase += DK) {
    __syncthreads();
    const float* za = &zt[(size_t)(m0 + mrow) * DIM + dbase + q];
    const float* wa = &w[(size_t)(k0 + mrow) * DIM + dbase + q];
    float4 a0 = *(const float4*)(za + 0), a1 = *(const float4*)(za + 4);
    float4 a2 = *(const float4*)(za + 8), a3 = *(const float4*)(za + 12);
    float4 b0 = *(const float4*)(wa + 0), b1 = *(const float4*)(wa + 4);
    float4 b2 = *(const float4*)(wa + 8), b3 = *(const float4*)(wa + 12);
    float* Ap = &As[mrow * PADL + q];
    float* Wp = &Ws[mrow * PADL + q];
    Ap[0] = a0.x; Ap[1] = a0.y; Ap[2] = a0.z; Ap[3] = a0.w;
    Ap[4] = a1.x; Ap[5] = a1.y; Ap[6] = a1.z; Ap[7] = a1.w;
    Ap[8] = a2.x; Ap[9] = a2.y; Ap[10] = a2.z; Ap[11] = a2.w;
    Ap[12] = a3.x; Ap[13] = a3.y; Ap[14] = a3.z; Ap[15] = a3.w;
    Wp[0] = b0.x; Wp[1] = b0.y; Wp[2] = b0.z; Wp[3] = b0.w;
    Wp[4] = b1.x; Wp[5] = b1.y; Wp[6] = b1.z; Wp[7] = b1.w;
    Wp[8] = b2.x; Wp[9] = b2.y; Wp[10] = b2.z; Wp[11] = b2.w;
    Wp[12] = b3.x; Wp[13] = b3.y; Wp[14] = b3.z; Wp[15] = b3.w;
    __syncthreads();
#pragma unroll
    for (int d = 0; d < DK; ++d) {
      float a[8], b[8];
#pragma unroll
      for (int i = 0; i < 4; ++i) {
        a[i]     = As[(ty * 4 + i) * PADL + d];
        a[4 + i] = As[(64 + ty * 4 + i) * PADL + d];
        b[i]     = Ws[(tx * 4 + i) * PADL + d];
        b[4 + i] = Ws[(64 + tx * 4 + i) * PADL + d];
      }
#pragma unroll
      for (int i = 0; i < 8; ++i)
#pragma unroll
        for (int j = 0; j < 8; ++j) acc[i][j] = fmaf(a[i], b[j], acc[i][j]);
    }
  }

  float sc[8];
  int cols[8];
#pragma unroll
  for (int j = 0; j < 8; ++j) {
    int c = (j < 4) ? tx * 4 + j : 64 + tx * 4 + (j - 4);
    cols[j] = k0 + c;
    sc[j] = wsq[cols[j]];
  }
#pragma unroll
  for (int i = 0; i < 8; ++i) {
    int r = (i < 4) ? ty * 4 + i : 64 + ty * 4 + (i - 4);
    unsigned long long bv = ~0ull;
#pragma unroll
    for (int j = 0; j < 8; ++j) {
      float score = fmaf(-2.0f, acc[i][j], sc[j]);
      unsigned u = __float_as_uint(score);
      u ^= (unsigned)(((int)u >> 31) | 0x80000000);
      unsigned long long p = ((unsigned long long)u << 32) | (unsigned)cols[j];
      bv = p < bv ? p : bv;
    }
    atomicMin(&best[r], bv);
  }
  __syncthreads();
  if (tid < TM) atomicMin(&packed[m0 + tid], best[tid]);
}

// ---------------- K3: indices + counts + z_q gather + loss + embed scatter ------
__global__ __launch_bounds__(256) void k_scatter(float* __restrict__ zt,
                                                 const float* __restrict__ w,
                                                 const unsigned long long* __restrict__ packed,
                                                 float* __restrict__ emb_out,
                                                 float* __restrict__ loss_sum,
                                                 float* __restrict__ out3,
                                                 float* __restrict__ counts) {
  int n = blockIdx.x, d = threadIdx.x;
  int k = (int)(packed[n] & 0xFFFFFFFFull) & (KC - 1);
  if (d == 0) {
    out3[n] = (float)k;
    atomicAdd(&counts[k], 1.0f);
  }
  float zv = zt[(size_t)n * DIM + d];
  float wv = w[(size_t)k * DIM + d];
  float diff = wv - zv;                       // z_q - z_perm
  zt[(size_t)n * DIM + d] = zv + diff;        // straight-through
  atomicAdd(&emb_out[(size_t)k * DIM + d], ONEMDECAY * zv);
  float v = diff * diff;
#pragma unroll
  for (int off = 32; off; off >>= 1) v += __shfl_down(v, off);
  __shared__ float red[4];
  if ((threadIdx.x & 63) == 0) red[threadIdx.x >> 6] = v;
  __syncthreads();
  if (threadIdx.x == 0) atomicAdd(loss_sum, red[0] + red[1] + red[2] + red[3]);
}

// ---------------- K4a: new_cluster_size, n_sum, perplexity partial --------------
__global__ void k_cs(const float* __restrict__ cs, const float* __restrict__ counts,
                     float* __restrict__ out5, float* __restrict__ scal) {
  int k = blockIdx.x * 256 + threadIdx.x;
  float c = counts[k];
  float ncs = cs[k] * DECAYF + ONEMDECAY * c;
  out5[k] = ncs;
  float p = c * (1.0f / (float)NZ);
  float t = p * logf(p + 1e-10f);
#pragma unroll
  for (int off = 32; off; off >>= 1) {
    ncs += __shfl_down(ncs, off);
    t += __shfl_down(t, off);
  }
  __shared__ float r1[4], r2[4];
  if ((threadIdx.x & 63) == 0) { r1[threadIdx.x >> 6] = ncs; r2[threadIdx.x >> 6] = t; }
  __syncthreads();
  if (threadIdx.x == 0) {
    atomicAdd(&scal[1], r1[0] + r1[1] + r1[2] + r1[3]);
    atomicAdd(&scal[2], r2[0] + r2[1] + r2[2] + r2[3]);
  }
}

// ---------------- K4b: new_weight + scalars -------------------------------------
__global__ void k_final(const float* __restrict__ emb_out, const float* __restrict__ out5,
                        const float* __restrict__ scal, float* __restrict__ out4,
                        float* __restrict__ out1, float* __restrict__ out2) {
  size_t i = (size_t)blockIdx.x * 256 + threadIdx.x;
  float n = scal[1];
  int k = (int)(i >> 8);
  float ncs = out5[k];
  float smoothed = (ncs + EPSF) / (n + (float)KC * EPSF) * n;
  out4[i] = emb_out[i] / smoothed;
  if (i == 0) {
    out1[0] = BETAF * scal[0] / (float)(NZ * DIM);
    out2[0] = expf(-scal[2]);
  }
}

extern "C" void kernel_launch(void* const* d_in, const int* in_sizes, int n_in,
                              void* d_out, int out_size, void* d_ws, size_t ws_size,
                              hipStream_t stream) {
  const float* z  = (const float*)d_in[0];
  const float* w  = (const float*)d_in[1];
  const float* cs = (const float*)d_in[2];
  const float* ea = (const float*)d_in[3];
  float* out = (float*)d_out;
  float* ws  = (float*)d_ws;

  if (ws_size < (size_t)WS_FLOATS_OLD * sizeof(float)) return;  // fail loudly
  const bool use_mfma = ws_size >= (size_t)WS_FLOATS_NEW * sizeof(float);

  float* zt      = ws + W_ZT;
  float* wsq     = ws + W_WSQ;
  float* counts  = ws + W_CNT;
  float* scal    = ws + W_SCAL;
  unsigned long long* packed = (unsigned long long*)(ws + W_PACKED);
  _Float16* Acat = (_Float16*)(ws + W_ACAT);
  _Float16* Bcat = (_Float16*)(ws + W_BCAT);

  float* out0 = out + O_ZQ;
  float* out1 = out + O_LOSS;
  float* out2 = out + O_PERP;
  float* out3 = out + O_IDX;
  float* out4 = out + O_NW;
  float* out5 = out + O_NCS;
  float* out6 = out + O_NEA;

  hipMemsetAsync(counts, 0, (16384 + 4) * sizeof(float), stream);   // counts + scal
  hipMemsetAsync(packed, 0xFF, (size_t)NZ * sizeof(unsigned long long), stream);

  if (use_mfma) {
    k_prep<true><<<KC / 4, 256, 0, stream>>>(w, ea, wsq, Bcat, out6);
    k_transpose_in<true><<<dim3(16, 4, NB), 256, 0, stream>>>(z, zt, Acat);
    k_argmin_mfma<<<(KC / GBN) * (NZ / GBM), 512, 0, stream>>>(Acat, Bcat, wsq, packed);
  } else {
    k_prep<false><<<KC / 4, 256, 0, stream>>>(w, ea, wsq, Bcat, out6);
    k_transpose_in<false><<<dim3(16, 4, NB), 256, 0, stream>>>(z, zt, Acat);
    k_argmin_fp32<<<dim3(KC / TN, NZ / TM), 256, 0, stream>>>(zt, w, wsq, packed);
  }
  k_scatter<<<NZ, 256, 0, stream>>>(zt, w, packed, out6, scal, out3, counts);
  k_cs<<<KC / 256, 256, 0, stream>>>(cs, counts, out5, scal);
  k_final<<<(KC * DIM) / 256, 256, 0, stream>>>(out6, out5, scal, out4, out1, out2);
  k_transpose_out<<<dim3(16, 4, NB), 256, 0, stream>>>(zt, out0);
}

// Round 9
// 418.646 us; speedup vs baseline: 1.1656x; 1.0324x over previous
//
#include <hip/hip_runtime.h>

// Problem constants (from setup_inputs): z (8,256,32,32), weight (16384,256)
#define NB   8
#define DIM  256
#define HW   1024          // 32*32
#define NZ   8192          // NB*HW flattened z rows
#define KC   16384         // codebook entries
#define DECAYF 0.99f
#define ONEMDECAY 0.01f
#define EPSF 1e-5f
#define BETAF 0.25f
// logical K = 768 ([ah|al|ah].[bh|bh|bl]); physical layout is dedup'd:
// Acat = [ah|al] (512), Bcat = [bh|bl] (512); segment->phys remap in STAGE.
#define APHYS 512

typedef _Float16 half8 __attribute__((ext_vector_type(8)));
typedef _Float16 half4 __attribute__((ext_vector_type(4)));
typedef float floatx4 __attribute__((ext_vector_type(4)));

// Output offsets (floats) in d_out, in reference return order
#define O_ZQ   0u
#define O_LOSS 2097152u
#define O_PERP 2097153u
#define O_IDX  2097154u
#define O_NW   2105346u
#define O_NCS  6299650u
#define O_NEA  6316034u

// ws layout (floats)
#define W_ZT     0u          // 8192*256 fp32
#define W_WSQ    2097152u    // 16384
#define W_CNT    2113536u    // 16384           (zeroed)
#define W_SCAL   2129920u    // 4: [0]=loss [1]=n_sum [2]=plogp (zeroed)
#define W_PACKED 2129924u    // 8192 u64 (byte off %8==0) (memset 0xFF)
#define W_ACAT   2146308u    // 8192*512 f16  (byte off %16==0)
#define W_BCAT   4243460u    // 16384*512 f16 (byte off %16==0)
#define WS_FLOATS_OLD 2146308u
#define WS_FLOATS_NEW 8437764u

// ---------------- K0: transpose z (b,c,h,w) -> zt[n][d] (+ f16 2-seg Acat) ------
template <bool SPLIT>
__global__ void k_transpose_in(const float* __restrict__ z, float* __restrict__ zt,
                               _Float16* __restrict__ Acat) {
  __shared__ float tile[64][65];
  int hwb = blockIdx.x * 64, db = blockIdx.y * 64, b = blockIdx.z;
  int lane = threadIdx.x & 63, sub = threadIdx.x >> 6;
#pragma unroll
  for (int i = 0; i < 16; ++i) {
    int dof = sub * 16 + i;
    tile[dof][lane] = z[((size_t)(b * DIM + db + dof)) * HW + hwb + lane];
  }
  __syncthreads();
#pragma unroll
  for (int i = 0; i < 16; ++i) {
    int hwof = sub * 16 + i;
    int n = b * HW + hwb + hwof;
    float val = tile[lane][hwof];
    zt[(size_t)n * DIM + db + lane] = val;
    if (SPLIT) {
      _Float16 h = (_Float16)val;
      _Float16 lo = (_Float16)(val - (float)h);
      size_t abase = (size_t)n * APHYS + db + lane;
      Acat[abase] = h;          // phys seg0 = ah
      Acat[abase + 256] = lo;   // phys seg1 = al
    }
  }
}

// ---------------- K5: transpose zt[n][d] (holds z_q_st) -> out0 (b,c,h,w) -------
__global__ void k_transpose_out(const float* __restrict__ zt, float* __restrict__ out0) {
  __shared__ float tile[64][65];
  int hwb = blockIdx.x * 64, db = blockIdx.y * 64, b = blockIdx.z;
  int lane = threadIdx.x & 63, sub = threadIdx.x >> 6;
#pragma unroll
  for (int i = 0; i < 16; ++i) {
    int hwof = sub * 16 + i;
    tile[hwof][lane] = zt[((size_t)(b * HW + hwb + hwof)) * DIM + db + lane];
  }
  __syncthreads();
#pragma unroll
  for (int i = 0; i < 16; ++i) {
    int dof = sub * 16 + i;
    out0[((size_t)(b * DIM + db + dof)) * HW + hwb + lane] = tile[lane][dof];
  }
}

// ---------------- K1: fused  wsq + 2-seg Bcat + out6 = 0.99*ea -------------------
template <bool SPLIT>
__global__ void k_prep(const float* __restrict__ w, const float* __restrict__ ea,
                       float* __restrict__ wsq, _Float16* __restrict__ Bcat,
                       float* __restrict__ out6) {
  int wave = threadIdx.x >> 6, lane = threadIdx.x & 63;
  int k = blockIdx.x * 4 + wave;
  float4 v = *(const float4*)&w[(size_t)k * DIM + lane * 4];
  float s = v.x * v.x + v.y * v.y + v.z * v.z + v.w * v.w;
#pragma unroll
  for (int off = 32; off; off >>= 1) s += __shfl_xor(s, off);
  if (lane == 0) wsq[k] = s;
  if (SPLIT) {
    half4 h = { (_Float16)v.x, (_Float16)v.y, (_Float16)v.z, (_Float16)v.w };
    half4 lo = { (_Float16)(v.x - (float)h.x), (_Float16)(v.y - (float)h.y),
                 (_Float16)(v.z - (float)h.z), (_Float16)(v.w - (float)h.w) };
    size_t bbase = (size_t)k * APHYS + lane * 4;
    *(half4*)&Bcat[bbase] = h;          // phys seg0 = bh
    *(half4*)&Bcat[bbase + 256] = lo;   // phys seg1 = bl
  }
  float4 e = *(const float4*)&ea[(size_t)k * DIM + lane * 4];
  float4 o = { DECAYF * e.x, DECAYF * e.y, DECAYF * e.z, DECAYF * e.w };
  *(float4*)&out6[(size_t)k * DIM + lane * 4] = o;
}

// ---------------- K2: 256x256 MFMA distance GEMM + fused argmin ------------------
// 8 waves (2M x 4N), per-wave 128x64 output. Phase-split K-loop; tile validity
// barrier (WAITVM; BAR) precedes ALL ds_reads of the tile (R8's race fix).
#define GBM 256
#define GBN 256
#define GBK 64
#define NSTEP 12            // logical K = 768

__device__ __forceinline__ void gload16(const _Float16* g, _Float16* lds) {
  __builtin_amdgcn_global_load_lds((__attribute__((address_space(1))) void*)g,
                                   (__attribute__((address_space(3))) void*)lds, 16, 0, 0);
}

#define WAITVM8   asm volatile("s_waitcnt vmcnt(8)" ::: "memory")
#define WAITVM0   asm volatile("s_waitcnt vmcnt(0)" ::: "memory")
#define BAR       __builtin_amdgcn_s_barrier()
#define LGKM0_SB  asm volatile("s_waitcnt lgkmcnt(0)" ::: "memory"); \
                  __builtin_amdgcn_sched_barrier(0)
#define PRIO1 __builtin_amdgcn_s_setprio(1)
#define PRIO0 __builtin_amdgcn_s_setprio(0)

__global__ __launch_bounds__(512, 2) void k_argmin_mfma(const _Float16* __restrict__ Acat,
                                                        const _Float16* __restrict__ Bcat,
                                                        const float* __restrict__ wsq,
                                                        unsigned long long* __restrict__ packed) {
  __shared__ __align__(16) _Float16 As[2][GBM * GBK];   // 64 KB
  __shared__ __align__(16) _Float16 Bs[2][GBN * GBK];   // 64 KB  (total 128 KB)
  const int tid = threadIdx.x;
  const int w = tid >> 6, l = tid & 63;
  const int lr = l & 15, lc = l >> 4;
  const int wr = w >> 2, wc = w & 3;
  // XCD ownership: xcd = bid&7 owns 8 n-panels (2 MB Bcat slice, L2-resident);
  // m-major order within the XCD reuses each A panel across its 8 n-panels.
  const int bid = (int)blockIdx.x;
  const int xcd = bid & 7, local = bid >> 3;
  const int m0 = (local >> 3) * GBM;
  const int n0 = (xcd * 8 + (local & 7)) * GBN;

  floatx4 acc[8][4];
#pragma unroll
  for (int i = 0; i < 8; ++i)
#pragma unroll
    for (int j = 0; j < 4; ++j) acc[i][j] = (floatx4){0.f, 0.f, 0.f, 0.f};

  // staging: LDS linear dest; global source pre-swizzled chunk^(row&7) so the
  // frag ds_read_b128 (row stride 128B) is bank-conflict-free.
  const int srow = (l >> 3);
  const int schk = (l & 7);

  // logical step -> physical offsets: seg = STEP>>2 (0:ah.bh 1:al.bh 2:ah.bl)
#define STAGE_A(BUF, STEP)                                                        \
  {                                                                               \
    const int seg_ = (STEP) >> 2, ksub_ = (STEP) & 3;                             \
    const int aoff_ = (seg_ == 1 ? 256 : 0) + ksub_ * 64;                         \
    _Pragma("unroll")                                                             \
    for (int c = 0; c < 4; ++c) {                                                 \
      int row = (w * 4 + c) * 8 + srow;                                           \
      int sc_ = schk ^ (row & 7);                                                 \
      gload16(Acat + (size_t)(m0 + row) * APHYS + aoff_ + sc_ * 8,                \
              &As[BUF][(w * 4 + c) * 512]);                                       \
    }                                                                             \
  }
#define STAGE_B(BUF, STEP)                                                        \
  {                                                                               \
    const int seg_ = (STEP) >> 2, ksub_ = (STEP) & 3;                             \
    const int boff_ = (seg_ == 2 ? 256 : 0) + ksub_ * 64;                         \
    _Pragma("unroll")                                                             \
    for (int c = 0; c < 4; ++c) {                                                 \
      int row = (w * 4 + c) * 8 + srow;                                           \
      int sc_ = schk ^ (row & 7);                                                 \
      gload16(Bcat + (size_t)(n0 + row) * APHYS + boff_ + sc_ * 8,                \
              &Bs[BUF][(w * 4 + c) * 512]);                                       \
    }                                                                             \
  }

#define READ_AF(KK, H)                                                            \
  _Pragma("unroll")                                                               \
  for (int mi = 0; mi < 4; ++mi) {                                                \
    int row = wr * 128 + ((H) * 4 + mi) * 16 + lr;                                \
    int ch = ((KK) * 4 + lc) ^ (row & 7);                                         \
    af[mi] = *(const half8*)&As[b][row * GBK + ch * 8];                           \
  }
#define READ_BF(KK)                                                               \
  _Pragma("unroll")                                                               \
  for (int ni = 0; ni < 4; ++ni) {                                                \
    int row = wc * 64 + ni * 16 + lr;                                             \
    int ch = ((KK) * 4 + lc) ^ (row & 7);                                         \
    bf[ni] = *(const half8*)&Bs[b][row * GBK + ch * 8];                           \
  }
#define MFMA16(H)                                                                 \
  _Pragma("unroll")                                                               \
  for (int mi = 0; mi < 4; ++mi)                                                  \
    _Pragma("unroll")                                                             \
    for (int ni = 0; ni < 4; ++ni)                                                \
      acc[(H) * 4 + mi][ni] =                                                     \
          __builtin_amdgcn_mfma_f32_16x16x32_f16(af[mi], bf[ni],                  \
                                                 acc[(H) * 4 + mi][ni], 0, 0, 0);

  // prologue: tiles 0 and 1
  STAGE_B(0, 0); STAGE_A(0, 0);
  STAGE_B(1, 1); STAGE_A(1, 1);

  for (int t = 0; t < NSTEP; ++t) {
    const int b = t & 1;
    if (t < NSTEP - 1) { WAITVM8; } else { WAITVM0; }
    BAR;                       // ALL waves' tile-t loads landed (the R8 race fix)
    half8 af[4], bf[4];
    // phase 0: kk0, acc rows 0-3 (+bf kk0)
    READ_AF(0, 0); READ_BF(0);
    LGKM0_SB; PRIO1; MFMA16(0); PRIO0; BAR;
    // phase 1: kk0, acc rows 4-7 (bf reused)
    READ_AF(0, 1);
    LGKM0_SB; PRIO1; MFMA16(1); PRIO0; BAR;
    // phase 2: kk1, acc rows 0-3 (+bf kk1)
    READ_AF(1, 0); READ_BF(1);
    LGKM0_SB; PRIO1; MFMA16(0); PRIO0; BAR;
    // phase 3: kk1, acc rows 4-7; all Bs[b] reads retired (phase-2 barrier) ->
    // stage next tile's B into this slot while MFMAs run.
    READ_AF(1, 1);
    if (t + 2 < NSTEP) STAGE_B(b, t + 2);
    LGKM0_SB; PRIO1; MFMA16(1); PRIO0; BAR;
    // all As[b] reads retired -> stage next tile's A.
    if (t + 2 < NSTEP) STAGE_A(b, t + 2);
  }
#undef STAGE_A
#undef STAGE_B
#undef READ_AF
#undef READ_BF
#undef MFMA16

  // epilogue: per-row argmin. C layout: col = lane&15, row = (lane>>4)*4 + reg.
  // best[] aliases the dead A buffer (final BAR above bounds all reads; WAITVM0
  // at the last iteration drained all in-flight LDS writes).
  unsigned long long* best = (unsigned long long*)&As[0][0];
  if (tid < GBM) best[tid] = ~0ull;
  __syncthreads();
  float sc4[4];
  int col4[4];
#pragma unroll
  for (int ni = 0; ni < 4; ++ni) {
    col4[ni] = n0 + wc * 64 + ni * 16 + lr;
    sc4[ni] = wsq[col4[ni]];
  }
#pragma unroll
  for (int mi = 0; mi < 8; ++mi) {
#pragma unroll
    for (int r = 0; r < 4; ++r) {
      unsigned long long bv = ~0ull;
#pragma unroll
      for (int ni = 0; ni < 4; ++ni) {
        float score = fmaf(-2.0f, acc[mi][ni][r], sc4[ni]);
        unsigned u = __float_as_uint(score);
        u ^= (unsigned)(((int)u >> 31) | 0x80000000);  // monotonic float->uint
        unsigned long long p = ((unsigned long long)u << 32) | (unsigned)col4[ni];
        bv = p < bv ? p : bv;
      }
#pragma unroll
      for (int off = 1; off < 16; off <<= 1) {
        unsigned long long o = __shfl_xor(bv, off);
        bv = o < bv ? o : bv;
      }
      if (lr == 0) atomicMin(&best[wr * 128 + mi * 16 + lc * 4 + r], bv);
    }
  }
  __syncthreads();
  if (tid < GBM) atomicMin(&packed[m0 + tid], best[tid]);
}

// ---------------- Fallback fp32 GEMM+argmin -------------------------------------
#define TM 128
#define TN 128
#define DK 32
#define PADL 33
__global__ __launch_bounds__(256) void k_argmin_fp32(const float* __restrict__ zt,
                                                     const float* __restrict__ w,
                                                     const float* __restrict__ wsq,
                                                     unsigned long long* __restrict__ packed) {
  __shared__ float As[TM * PADL];
  __shared__ float Ws[TN * PADL];
  __shared__ unsigned long long best[TM];
  const int tid = threadIdx.x;
  const int k0 = blockIdx.x * TN, m0 = blockIdx.y * TM;
  if (tid < TM) best[tid] = ~0ull;
  const int tx = tid & 15, ty = tid >> 4;
  const int mrow = tid & 127;
  const int q = (tid >> 7) * 16;

  float acc[8][8];
#pragma unroll
  for (int i = 0; i < 8; ++i)
#pragma unroll
    for (int j = 0; j < 8; ++j) acc[i][j] = 0.0f;

  for (int dbase = 0; dbase < DIM; dbase += DK) {
    __syncthreads();
    const float* za = &zt[(size_t)(m0 + mrow) * DIM + dbase + q];
    const float* wa = &w[(size_t)(k0 + mrow) * DIM + dbase + q];
    float4 a0 = *(const float4*)(za + 0), a1 = *(const float4*)(za + 4);
    float4 a2 = *(const float4*)(za + 8), a3 = *(const float4*)(za + 12);
    float4 b0 = *(const float4*)(wa + 0), b1 = *(const float4*)(wa + 4);
    float4 b2 = *(const float4*)(wa + 8), b3 = *(const float4*)(wa + 12);
    float* Ap = &As[mrow * PADL + q];
    float* Wp = &Ws[mrow * PADL + q];
    Ap[0] = a0.x; Ap[1] = a0.y; Ap[2] = a0.z; Ap[3] = a0.w;
    Ap[4] = a1.x; Ap[5] = a1.y; Ap[6] = a1.z; Ap[7] = a1.w;
    Ap[8] = a2.x; Ap[9] = a2.y; Ap[10] = a2.z; Ap[11] = a2.w;
    Ap[12] = a3.x; Ap[13] = a3.y; Ap[14] = a3.z; Ap[15] = a3.w;
    Wp[0] = b0.x; Wp[1] = b0.y; Wp[2] = b0.z; Wp[3] = b0.w;
    Wp[4] = b1.x; Wp[5] = b1.y; Wp[6] = b1.z; Wp[7] = b1.w;
    Wp[8] = b2.x; Wp[9] = b2.y; Wp[10] = b2.z; Wp[11] = b2.w;
    Wp[12] = b3.x; Wp[13] = b3.y; Wp[14] = b3.z; Wp[15] = b3.w;
    __syncthreads();
#pragma unroll
    for (int d = 0; d < DK; ++d) {
      float a[8], b[8];
#pragma unroll
      for (int i = 0; i < 4; ++i) {
        a[i]     = As[(ty * 4 + i) * PADL + d];
        a[4 + i] = As[(64 + ty * 4 + i) * PADL + d];
        b[i]     = Ws[(tx * 4 + i) * PADL + d];
        b[4 + i] = Ws[(64 + tx * 4 + i) * PADL + d];
      }
#pragma unroll
      for (int i = 0; i < 8; ++i)
#pragma unroll
        for (int j = 0; j < 8; ++j) acc[i][j] = fmaf(a[i], b[j], acc[i][j]);
    }
  }

  float sc[8];
  int cols[8];
#pragma unroll
  for (int j = 0; j < 8; ++j) {
    int c = (j < 4) ? tx * 4 + j : 64 + tx * 4 + (j - 4);
    cols[j] = k0 + c;
    sc[j] = wsq[cols[j]];
  }
#pragma unroll
  for (int i = 0; i < 8; ++i) {
    int r = (i < 4) ? ty * 4 + i : 64 + ty * 4 + (i - 4);
    unsigned long long bv = ~0ull;
#pragma unroll
    for (int j = 0; j < 8; ++j) {
      float score = fmaf(-2.0f, acc[i][j], sc[j]);
      unsigned u = __float_as_uint(score);
      u ^= (unsigned)(((int)u >> 31) | 0x80000000);
      unsigned long long p = ((unsigned long long)u << 32) | (unsigned)cols[j];
      bv = p < bv ? p : bv;
    }
    atomicMin(&best[r], bv);
  }
  __syncthreads();
  if (tid < TM) atomicMin(&packed[m0 + tid], best[tid]);
}

// ---------------- K3: indices + counts + z_q gather + loss + embed scatter ------
__global__ __launch_bounds__(256) void k_scatter(float* __restrict__ zt,
                                                 const float* __restrict__ w,
                                                 const unsigned long long* __restrict__ packed,
                                                 float* __restrict__ emb_out,
                                                 float* __restrict__ loss_sum,
                                                 float* __restrict__ out3,
                                                 float* __restrict__ counts) {
  int n = blockIdx.x, d = threadIdx.x;
  int k = (int)(packed[n] & 0xFFFFFFFFull) & (KC - 1);
  if (d == 0) {
    out3[n] = (float)k;
    atomicAdd(&counts[k], 1.0f);
  }
  float zv = zt[(size_t)n * DIM + d];
  float wv = w[(size_t)k * DIM + d];
  float diff = wv - zv;                       // z_q - z_perm
  zt[(size_t)n * DIM + d] = zv + diff;        // straight-through
  atomicAdd(&emb_out[(size_t)k * DIM + d], ONEMDECAY * zv);
  float v = diff * diff;
#pragma unroll
  for (int off = 32; off; off >>= 1) v += __shfl_down(v, off);
  __shared__ float red[4];
  if ((threadIdx.x & 63) == 0) red[threadIdx.x >> 6] = v;
  __syncthreads();
  if (threadIdx.x == 0) atomicAdd(loss_sum, red[0] + red[1] + red[2] + red[3]);
}

// ---------------- K4a: new_cluster_size, n_sum, perplexity partial --------------
__global__ void k_cs(const float* __restrict__ cs, const float* __restrict__ counts,
                     float* __restrict__ out5, float* __restrict__ scal) {
  int k = blockIdx.x * 256 + threadIdx.x;
  float c = counts[k];
  float ncs = cs[k] * DECAYF + ONEMDECAY * c;
  out5[k] = ncs;
  float p = c * (1.0f / (float)NZ);
  float t = p * logf(p + 1e-10f);
#pragma unroll
  for (int off = 32; off; off >>= 1) {
    ncs += __shfl_down(ncs, off);
    t += __shfl_down(t, off);
  }
  __shared__ float r1[4], r2[4];
  if ((threadIdx.x & 63) == 0) { r1[threadIdx.x >> 6] = ncs; r2[threadIdx.x >> 6] = t; }
  __syncthreads();
  if (threadIdx.x == 0) {
    atomicAdd(&scal[1], r1[0] + r1[1] + r1[2] + r1[3]);
    atomicAdd(&scal[2], r2[0] + r2[1] + r2[2] + r2[3]);
  }
}

// ---------------- K4b: new_weight + scalars -------------------------------------
__global__ void k_final(const float* __restrict__ emb_out, const float* __restrict__ out5,
                        const float* __restrict__ scal, float* __restrict__ out4,
                        float* __restrict__ out1, float* __restrict__ out2) {
  size_t i = (size_t)blockIdx.x * 256 + threadIdx.x;
  float n = scal[1];
  int k = (int)(i >> 8);
  float ncs = out5[k];
  float smoothed = (ncs + EPSF) / (n + (float)KC * EPSF) * n;
  out4[i] = emb_out[i] / smoothed;
  if (i == 0) {
    out1[0] = BETAF * scal[0] / (float)(NZ * DIM);
    out2[0] = expf(-scal[2]);
  }
}

extern "C" void kernel_launch(void* const* d_in, const int* in_sizes, int n_in,
                              void* d_out, int out_size, void* d_ws, size_t ws_size,
                              hipStream_t stream) {
  const float* z  = (const float*)d_in[0];
  const float* w  = (const float*)d_in[1];
  const float* cs = (const float*)d_in[2];
  const float* ea = (const float*)d_in[3];
  float* out = (float*)d_out;
  float* ws  = (float*)d_ws;

  if (ws_size < (size_t)WS_FLOATS_OLD * sizeof(float)) return;  // fail loudly
  const bool use_mfma = ws_size >= (size_t)WS_FLOATS_NEW * sizeof(float);

  float* zt      = ws + W_ZT;
  float* wsq     = ws + W_WSQ;
  float* counts  = ws + W_CNT;
  float* scal    = ws + W_SCAL;
  unsigned long long* packed = (unsigned long long*)(ws + W_PACKED);
  _Float16* Acat = (_Float16*)(ws + W_ACAT);
  _Float16* Bcat = (_Float16*)(ws + W_BCAT);

  float* out0 = out + O_ZQ;
  float* out1 = out + O_LOSS;
  float* out2 = out + O_PERP;
  float* out3 = out + O_IDX;
  float* out4 = out + O_NW;
  float* out5 = out + O_NCS;
  float* out6 = out + O_NEA;

  hipMemsetAsync(counts, 0, (16384 + 4) * sizeof(float), stream);   // counts + scal
  hipMemsetAsync(packed, 0xFF, (size_t)NZ * sizeof(unsigned long long), stream);

  if (use_mfma) {
    k_prep<true><<<KC / 4, 256, 0, stream>>>(w, ea, wsq, Bcat, out6);
    k_transpose_in<true><<<dim3(16, 4, NB), 256, 0, stream>>>(z, zt, Acat);
    k_argmin_mfma<<<(KC / GBN) * (NZ / GBM), 512, 0, stream>>>(Acat, Bcat, wsq, packed);
  } else {
    k_prep<false><<<KC / 4, 256, 0, stream>>>(w, ea, wsq, Bcat, out6);
    k_transpose_in<false><<<dim3(16, 4, NB), 256, 0, stream>>>(z, zt, Acat);
    k_argmin_fp32<<<dim3(KC / TN, NZ / TM), 256, 0, stream>>>(zt, w, wsq, packed);
  }
  k_scatter<<<NZ, 256, 0, stream>>>(zt, w, packed, out6, scal, out3, counts);
  k_cs<<<KC / 256, 256, 0, stream>>>(cs, counts, out5, scal);
  k_final<<<(KC * DIM) / 256, 256, 0, stream>>>(out6, out5, scal, out4, out1, out2);
  k_transpose_out<<<dim3(16, 4, NB), 256, 0, stream>>>(zt, out0);
}

// Round 10
// 393.701 us; speedup vs baseline: 1.2394x; 1.0634x over previous
//
#include <hip/hip_runtime.h>

// Problem constants (from setup_inputs): z (8,256,32,32), weight (16384,256)
#define NB   8
#define DIM  256
#define HW   1024          // 32*32
#define NZ   8192          // NB*HW flattened z rows
#define KC   16384         // codebook entries
#define DECAYF 0.99f
#define ONEMDECAY 0.01f
#define EPSF 1e-5f
#define BETAF 0.25f
// logical K = 768 ([ah|al|ah].[bh|bh|bl]); physical layout is dedup'd:
// Acat = [ah|al] (512), Bcat = [bh|bl] (512); segment->phys remap in STAGE.
#define APHYS 512

typedef _Float16 half8 __attribute__((ext_vector_type(8)));
typedef _Float16 half4 __attribute__((ext_vector_type(4)));
typedef float floatx4 __attribute__((ext_vector_type(4)));

// Output offsets (floats) in d_out, in reference return order
#define O_ZQ   0u
#define O_LOSS 2097152u
#define O_PERP 2097153u
#define O_IDX  2097154u
#define O_NW   2105346u
#define O_NCS  6299650u
#define O_NEA  6316034u

// ws layout (floats)
#define W_ZT     0u          // 8192*256 fp32
#define W_WSQ    2097152u    // 16384
#define W_CNT    2113536u    // 16384           (zeroed)
#define W_SCAL   2129920u    // 4: [0]=loss [1]=n_sum [2]=plogp (zeroed)
#define W_PACKED 2129924u    // 8192 u64 (byte off %8==0) (memset 0xFF)
#define W_ACAT   2146308u    // 8192*512 f16  (byte off %16==0)
#define W_BCAT   4243460u    // 16384*512 f16 (byte off %16==0)
#define WS_FLOATS_OLD 2146308u
#define WS_FLOATS_NEW 8437764u

// ---------------- K0: transpose z (b,c,h,w) -> zt[n][d] (+ f16 2-seg Acat) ------
template <bool SPLIT>
__global__ void k_transpose_in(const float* __restrict__ z, float* __restrict__ zt,
                               _Float16* __restrict__ Acat) {
  __shared__ float tile[64][65];
  int hwb = blockIdx.x * 64, db = blockIdx.y * 64, b = blockIdx.z;
  int lane = threadIdx.x & 63, sub = threadIdx.x >> 6;
#pragma unroll
  for (int i = 0; i < 16; ++i) {
    int dof = sub * 16 + i;
    tile[dof][lane] = z[((size_t)(b * DIM + db + dof)) * HW + hwb + lane];
  }
  __syncthreads();
#pragma unroll
  for (int i = 0; i < 16; ++i) {
    int hwof = sub * 16 + i;
    int n = b * HW + hwb + hwof;
    float val = tile[lane][hwof];
    zt[(size_t)n * DIM + db + lane] = val;
    if (SPLIT) {
      _Float16 h = (_Float16)val;
      _Float16 lo = (_Float16)(val - (float)h);
      size_t abase = (size_t)n * APHYS + db + lane;
      Acat[abase] = h;          // phys seg0 = ah
      Acat[abase + 256] = lo;   // phys seg1 = al
    }
  }
}

// ---------------- K5: transpose zt[n][d] (holds z_q_st) -> out0 (b,c,h,w) -------
__global__ void k_transpose_out(const float* __restrict__ zt, float* __restrict__ out0) {
  __shared__ float tile[64][65];
  int hwb = blockIdx.x * 64, db = blockIdx.y * 64, b = blockIdx.z;
  int lane = threadIdx.x & 63, sub = threadIdx.x >> 6;
#pragma unroll
  for (int i = 0; i < 16; ++i) {
    int hwof = sub * 16 + i;
    tile[hwof][lane] = zt[((size_t)(b * HW + hwb + hwof)) * DIM + db + lane];
  }
  __syncthreads();
#pragma unroll
  for (int i = 0; i < 16; ++i) {
    int dof = sub * 16 + i;
    out0[((size_t)(b * DIM + db + dof)) * HW + hwb + lane] = tile[lane][dof];
  }
}

// ---------------- K1: fused  wsq + 2-seg Bcat + out6 = 0.99*ea -------------------
template <bool SPLIT>
__global__ void k_prep(const float* __restrict__ w, const float* __restrict__ ea,
                       float* __restrict__ wsq, _Float16* __restrict__ Bcat,
                       float* __restrict__ out6) {
  int wave = threadIdx.x >> 6, lane = threadIdx.x & 63;
  int k = blockIdx.x * 4 + wave;
  float4 v = *(const float4*)&w[(size_t)k * DIM + lane * 4];
  float s = v.x * v.x + v.y * v.y + v.z * v.z + v.w * v.w;
#pragma unroll
  for (int off = 32; off; off >>= 1) s += __shfl_xor(s, off);
  if (lane == 0) wsq[k] = s;
  if (SPLIT) {
    half4 h = { (_Float16)v.x, (_Float16)v.y, (_Float16)v.z, (_Float16)v.w };
    half4 lo = { (_Float16)(v.x - (float)h.x), (_Float16)(v.y - (float)h.y),
                 (_Float16)(v.z - (float)h.z), (_Float16)(v.w - (float)h.w) };
    size_t bbase = (size_t)k * APHYS + lane * 4;
    *(half4*)&Bcat[bbase] = h;          // phys seg0 = bh
    *(half4*)&Bcat[bbase + 256] = lo;   // phys seg1 = bl
  }
  float4 e = *(const float4*)&ea[(size_t)k * DIM + lane * 4];
  float4 o = { DECAYF * e.x, DECAYF * e.y, DECAYF * e.z, DECAYF * e.w };
  *(float4*)&out6[(size_t)k * DIM + lane * 4] = o;
}

// ---------------- K2: 128x256 MFMA distance GEMM + fused argmin ------------------
// 8 waves (2M x 4N), per-wave output 64x64 (acc = 64 VGPR -> <=128 total regs ->
// 4 waves/SIMD -> 2 blocks/CU). Single-buffered 48 KB LDS; cross-block overlap
// (m97 mechanism) hides the stage->compute serialization.
#define GBM 128
#define GBN 256
#define GBK 64
#define NSTEP 12            // logical K = 768

__device__ __forceinline__ void gload16(const _Float16* g, _Float16* lds) {
  __builtin_amdgcn_global_load_lds((__attribute__((address_space(1))) void*)g,
                                   (__attribute__((address_space(3))) void*)lds, 16, 0, 0);
}

#define WAITVM0   asm volatile("s_waitcnt vmcnt(0)" ::: "memory")
#define WAITLGKM0 asm volatile("s_waitcnt lgkmcnt(0)" ::: "memory")
#define BAR       __builtin_amdgcn_s_barrier()

__global__ __launch_bounds__(512, 4) void k_argmin_mfma(const _Float16* __restrict__ Acat,
                                                        const _Float16* __restrict__ Bcat,
                                                        const float* __restrict__ wsq,
                                                        unsigned long long* __restrict__ packed) {
  __shared__ __align__(16) _Float16 As[GBM * GBK];   // 16 KB
  __shared__ __align__(16) _Float16 Bs[GBN * GBK];   // 32 KB  (total 48 KB)
  const int tid = threadIdx.x;
  const int w = tid >> 6, l = tid & 63;
  const int lr = l & 15, lc = l >> 4;
  const int wr = w >> 2, wc = w & 3;   // 2 x 4 wave grid, 64x64 per wave
  // XCD ownership: xcd = bid&7 owns 8 n-panels (L2-resident Bcat slice);
  // m-major order within the XCD reuses each A panel across its n-panels.
  const int bid = (int)blockIdx.x;
  const int xcd = bid & 7, local = bid >> 3;           // 4096 blocks total
  const int m0 = (local >> 3) * GBM;                   // 64 m-tiles
  const int n0 = (xcd * 8 + (local & 7)) * GBN;        // 64 n-tiles

  floatx4 acc[4][4];
#pragma unroll
  for (int i = 0; i < 4; ++i)
#pragma unroll
    for (int j = 0; j < 4; ++j) acc[i][j] = (floatx4){0.f, 0.f, 0.f, 0.f};

  // staging: LDS linear dest; global source pre-swizzled chunk^(row&7) so the
  // frag ds_read_b128 (row stride 128B) is bank-conflict-free.
  const int srow = (l >> 3);
  const int schk = (l & 7);

  // 6 gloads per thread per K-step: 2 A row-groups + 4 B row-groups of 8 rows.
  // logical step -> physical offsets: seg = STEP>>2 (0:ah.bh 1:al.bh 2:ah.bl)
#define STAGE(STEP)                                                               \
  {                                                                               \
    const int seg_ = (STEP) >> 2, ksub_ = (STEP) & 3;                             \
    const int aoff_ = (seg_ == 1 ? 256 : 0) + ksub_ * 64;                         \
    const int boff_ = (seg_ == 2 ? 256 : 0) + ksub_ * 64;                         \
    _Pragma("unroll")                                                             \
    for (int c = 0; c < 2; ++c) {                                                 \
      int row = (w * 2 + c) * 8 + srow;                                           \
      int sc_ = schk ^ (row & 7);                                                 \
      gload16(Acat + (size_t)(m0 + row) * APHYS + aoff_ + sc_ * 8,                \
              &As[(w * 2 + c) * 512]);                                            \
    }                                                                             \
    _Pragma("unroll")                                                             \
    for (int c = 0; c < 4; ++c) {                                                 \
      int row = (w * 4 + c) * 8 + srow;                                           \
      int sc_ = schk ^ (row & 7);                                                 \
      gload16(Bcat + (size_t)(n0 + row) * APHYS + boff_ + sc_ * 8,                \
              &Bs[(w * 4 + c) * 512]);                                            \
    }                                                                             \
  }

  for (int t = 0; t < NSTEP; ++t) {
    STAGE(t);
    WAITVM0;                 // my 6 stage-loads landed
    BAR;                     // everyone's landed -> tile valid
#pragma unroll
    for (int kk = 0; kk < 2; ++kk) {
      half8 af[4], bf[4];
#pragma unroll
      for (int mi = 0; mi < 4; ++mi) {
        int row = wr * 64 + mi * 16 + lr;
        int ch = (kk * 4 + lc) ^ (row & 7);
        af[mi] = *(const half8*)&As[row * GBK + ch * 8];
      }
#pragma unroll
      for (int ni = 0; ni < 4; ++ni) {
        int row = wc * 64 + ni * 16 + lr;
        int ch = (kk * 4 + lc) ^ (row & 7);
        bf[ni] = *(const half8*)&Bs[row * GBK + ch * 8];
      }
#pragma unroll
      for (int mi = 0; mi < 4; ++mi)
#pragma unroll
        for (int ni = 0; ni < 4; ++ni)
          acc[mi][ni] = __builtin_amdgcn_mfma_f32_16x16x32_f16(af[mi], bf[ni], acc[mi][ni], 0, 0, 0);
    }
    WAITLGKM0;               // my LDS reads retired
    BAR;                     // everyone done reading -> safe to overwrite
  }
#undef STAGE

  // epilogue: per-row argmin. C layout: col = lane&15, row = (lane>>4)*4 + reg.
  // best[] aliases the A buffer (final BAR above bounds all reads).
  unsigned long long* best = (unsigned long long*)&As[0];
  if (tid < GBM) best[tid] = ~0ull;
  __syncthreads();
  float sc4[4];
  int col4[4];
#pragma unroll
  for (int ni = 0; ni < 4; ++ni) {
    col4[ni] = n0 + wc * 64 + ni * 16 + lr;
    sc4[ni] = wsq[col4[ni]];
  }
#pragma unroll
  for (int mi = 0; mi < 4; ++mi) {
#pragma unroll
    for (int r = 0; r < 4; ++r) {
      unsigned long long bv = ~0ull;
#pragma unroll
      for (int ni = 0; ni < 4; ++ni) {
        float score = fmaf(-2.0f, acc[mi][ni][r], sc4[ni]);
        unsigned u = __float_as_uint(score);
        u ^= (unsigned)(((int)u >> 31) | 0x80000000);  // monotonic float->uint
        unsigned long long p = ((unsigned long long)u << 32) | (unsigned)col4[ni];
        bv = p < bv ? p : bv;
      }
#pragma unroll
      for (int off = 1; off < 16; off <<= 1) {
        unsigned long long o = __shfl_xor(bv, off);
        bv = o < bv ? o : bv;
      }
      if (lr == 0) atomicMin(&best[wr * 64 + mi * 16 + lc * 4 + r], bv);
    }
  }
  __syncthreads();
  if (tid < GBM) atomicMin(&packed[m0 + tid], best[tid]);
}

// ---------------- Fallback fp32 GEMM+argmin -------------------------------------
#define TM 128
#define TN 128
#define DK 32
#define PADL 33
__global__ __launch_bounds__(256) void k_argmin_fp32(const float* __restrict__ zt,
                                                     const float* __restrict__ w,
                                                     const float* __restrict__ wsq,
                                                     unsigned long long* __restrict__ packed) {
  __shared__ float As[TM * PADL];
  __shared__ float Ws[TN * PADL];
  __shared__ unsigned long long best[TM];
  const int tid = threadIdx.x;
  const int k0 = blockIdx.x * TN, m0 = blockIdx.y * TM;
  if (tid < TM) best[tid] = ~0ull;
  const int tx = tid & 15, ty = tid >> 4;
  const int mrow = tid & 127;
  const int q = (tid >> 7) * 16;

  float acc[8][8];
#pragma unroll
  for (int i = 0; i < 8; ++i)
#pragma unroll
    for (int j = 0; j < 8; ++j) acc[i][j] = 0.0f;

  for (int dbase = 0; dbase < DIM; dbase += DK) {
    __syncthreads();
    const float* za = &zt[(size_t)(m0 + mrow) * DIM + dbase + q];
    const float* wa = &w[(size_t)(k0 + mrow) * DIM + dbase + q];
    float4 a0 = *(const float4*)(za + 0), a1 = *(const float4*)(za + 4);
    float4 a2 = *(const float4*)(za + 8), a3 = *(const float4*)(za + 12);
    float4 b0 = *(const float4*)(wa + 0), b1 = *(const float4*)(wa + 4);
    float4 b2 = *(const float4*)(wa + 8), b3 = *(const float4*)(wa + 12);
    float* Ap = &As[mrow * PADL + q];
    float* Wp = &Ws[mrow * PADL + q];
    Ap[0] = a0.x; Ap[1] = a0.y; Ap[2] = a0.z; Ap[3] = a0.w;
    Ap[4] = a1.x; Ap[5] = a1.y; Ap[6] = a1.z; Ap[7] = a1.w;
    Ap[8] = a2.x; Ap[9] = a2.y; Ap[10] = a2.z; Ap[11] = a2.w;
    Ap[12] = a3.x; Ap[13] = a3.y; Ap[14] = a3.z; Ap[15] = a3.w;
    Wp[0] = b0.x; Wp[1] = b0.y; Wp[2] = b0.z; Wp[3] = b0.w;
    Wp[4] = b1.x; Wp[5] = b1.y; Wp[6] = b1.z; Wp[7] = b1.w;
    Wp[8] = b2.x; Wp[9] = b2.y; Wp[10] = b2.z; Wp[11] = b2.w;
    Wp[12] = b3.x; Wp[13] = b3.y; Wp[14] = b3.z; Wp[15] = b3.w;
    __syncthreads();
#pragma unroll
    for (int d = 0; d < DK; ++d) {
      float a[8], b[8];
#pragma unroll
      for (int i = 0; i < 4; ++i) {
        a[i]     = As[(ty * 4 + i) * PADL + d];
        a[4 + i] = As[(64 + ty * 4 + i) * PADL + d];
        b[i]     = Ws[(tx * 4 + i) * PADL + d];
        b[4 + i] = Ws[(64 + tx * 4 + i) * PADL + d];
      }
#pragma unroll
      for (int i = 0; i < 8; ++i)
#pragma unroll
        for (int j = 0; j < 8; ++j) acc[i][j] = fmaf(a[i], b[j], acc[i][j]);
    }
  }

  float sc[8];
  int cols[8];
#pragma unroll
  for (int j = 0; j < 8; ++j) {
    int c = (j < 4) ? tx * 4 + j : 64 + tx * 4 + (j - 4);
    cols[j] = k0 + c;
    sc[j] = wsq[cols[j]];
  }
#pragma unroll
  for (int i = 0; i < 8; ++i) {
    int r = (i < 4) ? ty * 4 + i : 64 + ty * 4 + (i - 4);
    unsigned long long bv = ~0ull;
#pragma unroll
    for (int j = 0; j < 8; ++j) {
      float score = fmaf(-2.0f, acc[i][j], sc[j]);
      unsigned u = __float_as_uint(score);
      u ^= (unsigned)(((int)u >> 31) | 0x80000000);
      unsigned long long p = ((unsigned long long)u << 32) | (unsigned)cols[j];
      bv = p < bv ? p : bv;
    }
    atomicMin(&best[r], bv);
  }
  __syncthreads();
  if (tid < TM) atomicMin(&packed[m0 + tid], best[tid]);
}

// ---------------- K3: indices + counts + z_q gather + loss + embed scatter ------
__global__ __launch_bounds__(256) void k_scatter(float* __restrict__ zt,
                                                 const float* __restrict__ w,
                                                 const unsigned long long* __restrict__ packed,
                                                 float* __restrict__ emb_out,
                                                 float* __restrict__ loss_sum,
                                                 float* __restrict__ out3,
                                                 float* __restrict__ counts) {
  int n = blockIdx.x, d = threadIdx.x;
  int k = (int)(packed[n] & 0xFFFFFFFFull) & (KC - 1);
  if (d == 0) {
    out3[n] = (float)k;
    atomicAdd(&counts[k], 1.0f);
  }
  float zv = zt[(size_t)n * DIM + d];
  float wv = w[(size_t)k * DIM + d];
  float diff = wv - zv;                       // z_q - z_perm
  zt[(size_t)n * DIM + d] = zv + diff;        // straight-through
  atomicAdd(&emb_out[(size_t)k * DIM + d], ONEMDECAY * zv);
  float v = diff * diff;
#pragma unroll
  for (int off = 32; off; off >>= 1) v += __shfl_down(v, off);
  __shared__ float red[4];
  if ((threadIdx.x & 63) == 0) red[threadIdx.x >> 6] = v;
  __syncthreads();
  if (threadIdx.x == 0) atomicAdd(loss_sum, red[0] + red[1] + red[2] + red[3]);
}

// ---------------- K4a: new_cluster_size, n_sum, perplexity partial --------------
__global__ void k_cs(const float* __restrict__ cs, const float* __restrict__ counts,
                     float* __restrict__ out5, float* __restrict__ scal) {
  int k = blockIdx.x * 256 + threadIdx.x;
  float c = counts[k];
  float ncs = cs[k] * DECAYF + ONEMDECAY * c;
  out5[k] = ncs;
  float p = c * (1.0f / (float)NZ);
  float t = p * logf(p + 1e-10f);
#pragma unroll
  for (int off = 32; off; off >>= 1) {
    ncs += __shfl_down(ncs, off);
    t += __shfl_down(t, off);
  }
  __shared__ float r1[4], r2[4];
  if ((threadIdx.x & 63) == 0) { r1[threadIdx.x >> 6] = ncs; r2[threadIdx.x >> 6] = t; }
  __syncthreads();
  if (threadIdx.x == 0) {
    atomicAdd(&scal[1], r1[0] + r1[1] + r1[2] + r1[3]);
    atomicAdd(&scal[2], r2[0] + r2[1] + r2[2] + r2[3]);
  }
}

// ---------------- K4b: new_weight + scalars -------------------------------------
__global__ void k_final(const float* __restrict__ emb_out, const float* __restrict__ out5,
                        const float* __restrict__ scal, float* __restrict__ out4,
                        float* __restrict__ out1, float* __restrict__ out2) {
  size_t i = (size_t)blockIdx.x * 256 + threadIdx.x;
  float n = scal[1];
  int k = (int)(i >> 8);
  float ncs = out5[k];
  float smoothed = (ncs + EPSF) / (n + (float)KC * EPSF) * n;
  out4[i] = emb_out[i] / smoothed;
  if (i == 0) {
    out1[0] = BETAF * scal[0] / (float)(NZ * DIM);
    out2[0] = expf(-scal[2]);
  }
}

extern "C" void kernel_launch(void* const* d_in, const int* in_sizes, int n_in,
                              void* d_out, int out_size, void* d_ws, size_t ws_size,
                              hipStream_t stream) {
  const float* z  = (const float*)d_in[0];
  const float* w  = (const float*)d_in[1];
  const float* cs = (const float*)d_in[2];
  const float* ea = (const float*)d_in[3];
  float* out = (float*)d_out;
  float* ws  = (float*)d_ws;

  if (ws_size < (size_t)WS_FLOATS_OLD * sizeof(float)) return;  // fail loudly
  const bool use_mfma = ws_size >= (size_t)WS_FLOATS_NEW * sizeof(float);

  float* zt      = ws + W_ZT;
  float* wsq     = ws + W_WSQ;
  float* counts  = ws + W_CNT;
  float* scal    = ws + W_SCAL;
  unsigned long long* packed = (unsigned long long*)(ws + W_PACKED);
  _Float16* Acat = (_Float16*)(ws + W_ACAT);
  _Float16* Bcat = (_Float16*)(ws + W_BCAT);

  float* out0 = out + O_ZQ;
  float* out1 = out + O_LOSS;
  float* out2 = out + O_PERP;
  float* out3 = out + O_IDX;
  float* out4 = out + O_NW;
  float* out5 = out + O_NCS;
  float* out6 = out + O_NEA;

  hipMemsetAsync(counts, 0, (16384 + 4) * sizeof(float), stream);   // counts + scal
  hipMemsetAsync(packed, 0xFF, (size_t)NZ * sizeof(unsigned long long), stream);

  if (use_mfma) {
    k_prep<true><<<KC / 4, 256, 0, stream>>>(w, ea, wsq, Bcat, out6);
    k_transpose_in<true><<<dim3(16, 4, NB), 256, 0, stream>>>(z, zt, Acat);
    k_argmin_mfma<<<(KC / GBN) * (NZ / GBM), 512, 0, stream>>>(Acat, Bcat, wsq, packed);
  } else {
    k_prep<false><<<KC / 4, 256, 0, stream>>>(w, ea, wsq, Bcat, out6);
    k_transpose_in<false><<<dim3(16, 4, NB), 256, 0, stream>>>(z, zt, Acat);
    k_argmin_fp32<<<dim3(KC / TN, NZ / TM), 256, 0, stream>>>(zt, w, wsq, packed);
  }
  k_scatter<<<NZ, 256, 0, stream>>>(zt, w, packed, out6, scal, out3, counts);
  k_cs<<<KC / 256, 256, 0, stream>>>(cs, counts, out5, scal);
  k_final<<<(KC * DIM) / 256, 256, 0, stream>>>(out6, out5, scal, out4, out1, out2);
  k_transpose_out<<<dim3(16, 4, NB), 256, 0, stream>>>(zt, out0);
}